// Round 1
// baseline (1455.101 us; speedup 1.0000x reference)
//
#include <hip/hip_runtime.h>
#include <cstdint>
#include <cstddef>

#define RFL(x) __builtin_amdgcn_readfirstlane(x)

constexpr int E  = 64;     // channels in SS2D stage
constexpr int Rr = 32;     // low rank
constexpr int Nn = 64;     // state dim
constexpr int Lt = 3136;   // 56*56 tokens
constexpr int NC = 16;     // scan chunks
constexpr int CL = 196;    // Lt/NC
constexpr int PD = 192;    // packed proj row: [u(32) | dt(32) | B(64) | C(64)]

// ---------------- weight transpose: wT[i][c][o] ----------------
__global__ __launch_bounds__(256) void k_wtrans(const float* __restrict__ in_w,
    const float* __restrict__ dt_w, const float* __restrict__ B_w,
    const float* __restrict__ C_w, float* __restrict__ wT) {
  int idx = blockIdx.x * 256 + threadIdx.x;
  if (idx >= 3 * 64 * PD) return;
  int o = idx % PD; int c = (idx / PD) & 63; int i = idx / (PD * 64);
  float v;
  if (o < 32)       v = in_w[(i * 32 + o) * 64 + c];
  else if (o < 64)  v = dt_w[(i * 32 + (o - 32)) * 64 + c];
  else if (o < 128) v = B_w[(i * 64 + (o - 64)) * 64 + c];
  else              v = C_w[(i * 64 + (o - 128)) * 64 + c];
  wT[idx] = v;
}

// ---------------- conv3x3 stride2 pad1 + BN + SiLU (naive direct) ----------------
__global__ __launch_bounds__(256) void k_conv_bn_silu(const float* __restrict__ x,
    const float* __restrict__ w, const float* __restrict__ g, const float* __restrict__ bb,
    const float* __restrict__ m, const float* __restrict__ vv, float* __restrict__ out,
    int B, int Cin, int Hin, int Win, int Cout, int Hout, int Wout) {
  int idx = blockIdx.x * 256 + threadIdx.x;
  int total = B * Cout * Hout * Wout;
  if (idx >= total) return;
  int ow = idx % Wout; int oh = (idx / Wout) % Hout;
  int co = (idx / (Wout * Hout)) % Cout; int b = idx / (Wout * Hout * Cout);
  const float* wc = w + (size_t)co * Cin * 9;
  int ih0 = oh * 2 - 1, iw0 = ow * 2 - 1;
  float acc = 0.f;
  for (int ci = 0; ci < Cin; ++ci) {
    const float* xp = x + ((size_t)(b * Cin + ci) * Hin) * Win;
    const float* wp = wc + ci * 9;
#pragma unroll
    for (int kh = 0; kh < 3; ++kh) {
      int ih = ih0 + kh;
      if ((unsigned)ih >= (unsigned)Hin) continue;
      const float* xr = xp + (size_t)ih * Win;
#pragma unroll
      for (int kw = 0; kw < 3; ++kw) {
        int iw = iw0 + kw;
        if ((unsigned)iw >= (unsigned)Win) continue;
        acc = fmaf(xr[iw], wp[kh * 3 + kw], acc);
      }
    }
  }
  float scale = g[co] * rsqrtf(vv[co] + 1e-5f);
  float y = (acc - m[co]) * scale + bb[co];
  out[idx] = y / (1.f + __expf(-y));
}

// ---------------- token projections: x[b][c][l] -> P[b][l][192] ----------------
// P row layout: [0,32)=u, [32,64)=softplus(dt_raw+dt_b), [64,128)=Bt, [128,192)=Ct
__global__ __launch_bounds__(256) void k_proj(const float* __restrict__ xin,
    const float* __restrict__ wT, const float* __restrict__ dt_b, float* __restrict__ P) {
  // blockIdx: b = &7 (XCD-pin), tile = >>3 (49 tiles of 64 tokens)
  int b = blockIdx.x & 7, tl = blockIdx.x >> 3;
  int l0 = tl * 64;
  __shared__ float xl[64 * 65];
  int tid = threadIdx.x;
  for (int k = 0; k < 16; ++k) {
    int idx = k * 256 + tid; int c = idx >> 6, li = idx & 63;
    xl[c * 65 + li] = xin[(size_t)(b * 64 + c) * Lt + l0 + li];
  }
  __syncthreads();
  int tok = tid & 63;
  int og = RFL(tid >> 6);            // wave-uniform output group, 48 outputs each
  const float* wbase = wT + og * 48;
  float acc[48];
#pragma unroll
  for (int j = 0; j < 48; ++j) acc[j] = 0.f;
  for (int c = 0; c < 64; ++c) {
    float xv = xl[c * 65 + tok];
    const float4* w4 = (const float4*)(wbase + c * PD);
#pragma unroll
    for (int j = 0; j < 12; ++j) {
      float4 wv = __ldg(w4 + j);
      acc[4 * j + 0] = fmaf(xv, wv.x, acc[4 * j + 0]);
      acc[4 * j + 1] = fmaf(xv, wv.y, acc[4 * j + 1]);
      acc[4 * j + 2] = fmaf(xv, wv.z, acc[4 * j + 2]);
      acc[4 * j + 3] = fmaf(xv, wv.w, acc[4 * j + 3]);
    }
  }
  float* dst = P + ((size_t)(b * Lt + l0 + tok)) * PD + og * 48;
#pragma unroll
  for (int j = 0; j < 48; ++j) {
    int o = og * 48 + j;
    float v = acc[j];
    if (o >= 32 && o < 64) {
      v += dt_b[o - 32];
      v = fmaxf(v, 0.f) + log1pf(__expf(-fabsf(v)));   // softplus
    }
    dst[j] = v;
  }
}

// ---------------- scan phase 1: per-chunk local scan summary ----------------
__global__ __launch_bounds__(256) void k_scan1(const float* __restrict__ P,
    const float* __restrict__ A_log, float* __restrict__ hfin, float* __restrict__ Pc) {
  int b = blockIdx.x & 7, grp = blockIdx.x >> 3;          // 1024 blocks
  int s = RFL(grp * 4 + (threadIdx.x >> 6));              // 0..511
  int r = s >> 4, c = s & 15;
  int n = threadIdx.x & 63;
  float a = -__expf(A_log[r * 64 + n]);
  const float* base = P + ((size_t)(b * Lt + c * CL)) * PD;
  float h = 0.f, sdt = 0.f;
#pragma unroll 4
  for (int t = 0; t < CL; ++t) {
    const float* row = base + t * PD;
    float dt = row[32 + r];
    float u  = row[r];
    float bt = row[64 + n];
    h = fmaf(__expf(dt * a), h, (dt * u) * bt);
    sdt += dt;
  }
  int o = ((b * 32 + r) * 16 + c) * 64 + n;
  hfin[o] = h;
  Pc[o] = __expf(a * sdt);
}

// ---------------- scan phase 2: combine chunk summaries -> chunk-start states ----------------
__global__ __launch_bounds__(256) void k_scan2(const float* __restrict__ hfin,
    const float* __restrict__ Pc, float* __restrict__ Hs) {
  int wid = blockIdx.x * 4 + (threadIdx.x >> 6);          // 0..255 = (b,r)
  int b = wid >> 5, r = wid & 31, n = threadIdx.x & 63;
  float H = 0.f;
  int base = ((b * 32 + r) * 16) * 64 + n;
#pragma unroll
  for (int c = 0; c < 16; ++c) {
    Hs[base + c * 64] = H;
    H = fmaf(Pc[base + c * 64], H, hfin[base + c * 64]);
  }
}

// ---------------- scan phase 3: emit states + y ----------------
__global__ __launch_bounds__(256) void k_scan3(const float* __restrict__ P,
    const float* __restrict__ A_log, const float* __restrict__ Hs,
    const float* __restrict__ Dp, float* __restrict__ states, float* __restrict__ y) {
  __shared__ __align__(16) float ylds[4][32 * 68];
  int b = blockIdx.x & 7, grp = blockIdx.x >> 3;
  int wslot = RFL(threadIdx.x >> 6);
  int s = RFL(grp * 4 + wslot);
  int r = s >> 4, c = s & 15;
  int n = threadIdx.x & 63;
  float a = -__expf(A_log[r * 64 + n]);
  float Dr = Dp[r];
  const float* base = P + ((size_t)(b * Lt + c * CL)) * PD;
  float h = Hs[((b * 32 + r) * 16 + c) * 64 + n];
  float* st = states + ((size_t)(b * Lt + c * CL) * 32 + r) * 64 + n;
  float* yrow = y + (size_t)(b * 32 + r) * Lt + c * CL;
  float* yl = &ylds[wslot][0];
  for (int t0 = 0; t0 < CL; t0 += 32) {
    int BT = min(32, CL - t0);
#pragma unroll 4
    for (int t = t0; t < t0 + BT; ++t) {
      const float* row = base + t * PD;
      float dt = row[32 + r];
      float u  = row[r];
      float bt = row[64 + n];
      float ct = row[128 + n];
      h = fmaf(__expf(dt * a), h, (dt * u) * bt);
      st[(size_t)t * 2048] = h;
      yl[(t - t0) * 68 + n] = h * ct;
    }
    if (n < BT) {
      const float4* rp = (const float4*)(yl + n * 68);
      float s0 = 0.f, s1 = 0.f, s2 = 0.f, s3 = 0.f;
#pragma unroll
      for (int k = 0; k < 16; ++k) {
        float4 pv = rp[k];
        s0 += pv.x; s1 += pv.y; s2 += pv.z; s3 += pv.w;
      }
      float sum = (s0 + s1) + (s2 + s3);
      float uu = base[(size_t)(t0 + n) * PD + r];
      yrow[t0 + n] = sum + Dr * uu;
    }
  }
}

// ---------------- out projection + residual: xout = xin + y @ out_w^T ----------------
__global__ __launch_bounds__(256) void k_outproj(const float* __restrict__ xin,
    const float* __restrict__ y, const float* __restrict__ ow, float* __restrict__ xout) {
  __shared__ float ylds[32 * 64];
  int b = blockIdx.x & 7, tl = blockIdx.x >> 3;
  int l0 = tl * 64;
  int tid = threadIdx.x;
  for (int k = 0; k < 8; ++k) {
    int idx = k * 256 + tid; int r = idx >> 6, li = idx & 63;
    ylds[r * 64 + li] = y[(size_t)(b * 32 + r) * Lt + l0 + li];
  }
  __syncthreads();
  int li = tid & 63, cg = RFL(tid >> 6);
  for (int cc = 0; cc < 16; ++cc) {
    int ci = cg * 16 + cc;
    float acc = xin[(size_t)(b * 64 + ci) * Lt + l0 + li];
    const float4* w4 = (const float4*)(ow + ci * 32);
#pragma unroll
    for (int r4 = 0; r4 < 8; ++r4) {
      float4 wv = __ldg(w4 + r4);
      acc = fmaf(ylds[(r4 * 4 + 0) * 64 + li], wv.x, acc);
      acc = fmaf(ylds[(r4 * 4 + 1) * 64 + li], wv.y, acc);
      acc = fmaf(ylds[(r4 * 4 + 2) * 64 + li], wv.z, acc);
      acc = fmaf(ylds[(r4 * 4 + 3) * 64 + li], wv.w, acc);
    }
    xout[(size_t)(b * 64 + ci) * Lt + l0 + li] = acc;
  }
}

extern "C" void kernel_launch(void* const* d_in, const int* in_sizes, int n_in,
                              void* d_out, int out_size, void* d_ws, size_t ws_size,
                              hipStream_t stream) {
  const float* x      = (const float*)d_in[0];
  const float* stem_w = (const float*)d_in[1];
  const float* stem_g = (const float*)d_in[2];
  const float* stem_b = (const float*)d_in[3];
  const float* stem_m = (const float*)d_in[4];
  const float* stem_v = (const float*)d_in[5];
  const float* in_w   = (const float*)d_in[6];
  const float* dt_w   = (const float*)d_in[7];
  const float* dt_b   = (const float*)d_in[8];
  const float* B_w    = (const float*)d_in[9];
  const float* C_w    = (const float*)d_in[10];
  const float* A_log  = (const float*)d_in[11];
  const float* Dp     = (const float*)d_in[12];
  const float* out_w  = (const float*)d_in[13];
  const float* p4_w   = (const float*)d_in[14];
  const float* p4_g   = (const float*)d_in[15];
  const float* p4_b   = (const float*)d_in[16];
  const float* p4_m   = (const float*)d_in[17];
  const float* p4_v   = (const float*)d_in[18];
  const float* p5_w   = (const float*)d_in[19];
  const float* p5_g   = (const float*)d_in[20];
  const float* p5_b   = (const float*)d_in[21];
  const float* p5_m   = (const float*)d_in[22];
  const float* p5_v   = (const float*)d_in[23];

  float* out = (float*)d_out;
  float* wsf = (float*)d_ws;

  // output regions
  float* p3out = out;                       // 8*64*56*56  = 1605632
  float* p4out = out + 1605632;             // 8*128*28*28 =  802816
  float* p5out = out + 2408448;             // 8*256*14*14 =  401408
  float* stout = out + 2809856;             // 3*8*3136*32*64

  // workspace layout (floats): total 9,654,272 (~38.6 MB)
  float* x0   = wsf;                  // 1605632
  float* x1   = wsf + 1605632;        // 1605632
  float* Pb   = wsf + 3211264;        // 4816896 (8*3136*192)
  float* yb   = wsf + 8028160;        //  802816 (8*32*3136)
  float* hfin = wsf + 8830976;        //  262144
  float* Pc   = wsf + 9093120;        //  262144
  float* Hs   = wsf + 9355264;        //  262144
  float* wT   = wsf + 9617408;        //   36864 (3*64*192)

  k_wtrans<<<144, 256, 0, stream>>>(in_w, dt_w, B_w, C_w, wT);

  // stem: [8,32,112,112] -> [8,64,56,56]
  k_conv_bn_silu<<<6272, 256, 0, stream>>>(x, stem_w, stem_g, stem_b, stem_m, stem_v,
                                           x0, 8, 32, 112, 112, 64, 56, 56);

  const float* xi = x0;
  for (int i = 0; i < 3; ++i) {
    k_proj<<<392, 256, 0, stream>>>(xi, wT + i * 64 * PD, dt_b + i * 32, Pb);
    k_scan1<<<1024, 256, 0, stream>>>(Pb, A_log + i * 2048, hfin, Pc);
    k_scan2<<<64, 256, 0, stream>>>(hfin, Pc, Hs);
    k_scan3<<<1024, 256, 0, stream>>>(Pb, A_log + i * 2048, Hs, Dp + i * 32,
                                      stout + (size_t)i * 51380224, yb);
    float* dst = (i == 2) ? p3out : ((i == 0) ? x1 : x0);
    k_outproj<<<392, 256, 0, stream>>>(xi, yb, out_w + i * 2048, dst);
    xi = dst;
  }

  // p4: [8,64,56,56] -> [8,128,28,28]
  k_conv_bn_silu<<<3136, 256, 0, stream>>>(p3out, p4_w, p4_g, p4_b, p4_m, p4_v,
                                           p4out, 8, 64, 56, 56, 128, 28, 28);
  // p5: [8,128,28,28] -> [8,256,14,14]
  k_conv_bn_silu<<<1568, 256, 0, stream>>>(p4out, p5_w, p5_g, p5_b, p5_m, p5_v,
                                           p5out, 8, 128, 28, 28, 256, 14, 14);
}

// Round 2
// 779.638 us; speedup vs baseline: 1.8664x; 1.8664x over previous
//
#include <hip/hip_runtime.h>
#include <cstdint>
#include <cstddef>

#define RFL(x) __builtin_amdgcn_readfirstlane(x)

constexpr int E  = 64;     // channels in SS2D stage
constexpr int Rr = 32;     // low rank
constexpr int Nn = 64;     // state dim
constexpr int Lt = 3136;   // 56*56 tokens
constexpr int NC = 16;     // scan chunks
constexpr int CL = 196;    // Lt/NC
constexpr int PD = 192;    // packed proj row: [u(32) | dt(32) | B(64) | C(64)]

// ---------------- SS2D weight transpose: wT[i][c][o] ----------------
__global__ __launch_bounds__(256) void k_wtrans(const float* __restrict__ in_w,
    const float* __restrict__ dt_w, const float* __restrict__ B_w,
    const float* __restrict__ C_w, float* __restrict__ wT) {
  int idx = blockIdx.x * 256 + threadIdx.x;
  if (idx >= 3 * 64 * PD) return;
  int o = idx % PD; int c = (idx / PD) & 63; int i = idx / (PD * 64);
  float v;
  if (o < 32)       v = in_w[(i * 32 + o) * 64 + c];
  else if (o < 64)  v = dt_w[(i * 32 + (o - 32)) * 64 + c];
  else if (o < 128) v = B_w[(i * 64 + (o - 64)) * 64 + c];
  else              v = C_w[(i * 64 + (o - 128)) * 64 + c];
  wT[idx] = v;
}

// ---------------- conv weight transpose: w[Cout][Cin][3][3] -> wT[Cin*9][Cout] ----------------
__global__ __launch_bounds__(256) void k_cwt(const float* __restrict__ w,
    float* __restrict__ wT, int Cout, int Cin) {
  int idx = blockIdx.x * 256 + threadIdx.x;
  if (idx >= Cout * Cin * 9) return;
  int co = idx % Cout; int k9 = (idx / Cout) % 9; int ci = idx / (Cout * 9);
  wT[idx] = w[((size_t)co * Cin + ci) * 9 + k9];
}

// ---------------- conv3x3 s2 p1 + BN + SiLU, co-per-lane, 4 ow per thread ----------------
// wT layout [Cin*9][Cout]. Block: CPB co-lanes x SPB spatial tiles (CPB*SPB=256).
__global__ __launch_bounds__(256) void k_conv4(const float* __restrict__ x,
    const float* __restrict__ wT, const float* __restrict__ g, const float* __restrict__ bb,
    const float* __restrict__ m, const float* __restrict__ vv, float* __restrict__ out,
    int B, int Cin, int Hin, int Win, int Cout, int Hout, int Wout,
    int lg_cpb, int Wt) {
  int co = threadIdx.x & ((1 << lg_cpb) - 1);
  int sl = threadIdx.x >> lg_cpb;
  int spb = 256 >> lg_cpb;
  int gs = blockIdx.x * spb + sl;
  int t = gs % Wt; int oh = (gs / Wt) % Hout; int b = gs / (Wt * Hout);
  int ow0 = t * 4;
  int iw0 = ow0 * 2;
  bool fullt = (ow0 + 4 <= Wout);
  int ih0 = oh * 2 - 1;
  const float* xin = x + (size_t)b * Cin * Hin * Win;

  float acc0 = 0.f, acc1 = 0.f, acc2 = 0.f, acc3 = 0.f;
#pragma unroll 2
  for (int ci = 0; ci < Cin; ++ci) {
    const float* xp = xin + (size_t)ci * Hin * Win;
    const float* wp = wT + (size_t)(ci * 9) * Cout + co;
#pragma unroll
    for (int kh = 0; kh < 3; ++kh) {
      int ih = ih0 + kh;
      if ((unsigned)ih >= (unsigned)Hin) continue;
      const float* xr = xp + (size_t)ih * Win;
      float l = (iw0 > 0) ? xr[iw0 - 1] : 0.f;
      float4 A4 = *(const float4*)(xr + iw0);
      float4 B4 = fullt ? *(const float4*)(xr + iw0 + 4) : make_float4(0.f, 0.f, 0.f, 0.f);
      float w0 = wp[(size_t)(kh * 3 + 0) * Cout];
      float w1 = wp[(size_t)(kh * 3 + 1) * Cout];
      float w2 = wp[(size_t)(kh * 3 + 2) * Cout];
      acc0 = fmaf(l,    w0, acc0); acc0 = fmaf(A4.x, w1, acc0); acc0 = fmaf(A4.y, w2, acc0);
      acc1 = fmaf(A4.y, w0, acc1); acc1 = fmaf(A4.z, w1, acc1); acc1 = fmaf(A4.w, w2, acc1);
      acc2 = fmaf(A4.w, w0, acc2); acc2 = fmaf(B4.x, w1, acc2); acc2 = fmaf(B4.y, w2, acc2);
      acc3 = fmaf(B4.y, w0, acc3); acc3 = fmaf(B4.z, w1, acc3); acc3 = fmaf(B4.w, w2, acc3);
    }
  }
  float scale = g[co] * rsqrtf(vv[co] + 1e-5f);
  float mb = m[co], bc = bb[co];
  size_t obase = (((size_t)b * Cout + co) * Hout + oh) * Wout + ow0;
  float ys[4] = {acc0, acc1, acc2, acc3};
#pragma unroll
  for (int o = 0; o < 4; ++o) {
    if (ow0 + o < Wout) {
      float y = (ys[o] - mb) * scale + bc;
      out[obase + o] = y / (1.f + __expf(-y));
    }
  }
}

// ---------------- token projections: x[b][c][l] -> P[b][l][192] ----------------
__global__ __launch_bounds__(256) void k_proj(const float* __restrict__ xin,
    const float* __restrict__ wT, const float* __restrict__ dt_b, float* __restrict__ P) {
  int b = blockIdx.x & 7, tl = blockIdx.x >> 3;
  int l0 = tl * 64;
  __shared__ float xl[64 * 65];
  int tid = threadIdx.x;
  for (int k = 0; k < 16; ++k) {
    int idx = k * 256 + tid; int c = idx >> 6, li = idx & 63;
    xl[c * 65 + li] = xin[(size_t)(b * 64 + c) * Lt + l0 + li];
  }
  __syncthreads();
  int tok = tid & 63;
  int og = RFL(tid >> 6);
  const float* wbase = wT + og * 48;
  float acc[48];
#pragma unroll
  for (int j = 0; j < 48; ++j) acc[j] = 0.f;
  for (int c = 0; c < 64; ++c) {
    float xv = xl[c * 65 + tok];
    const float4* w4 = (const float4*)(wbase + c * PD);
#pragma unroll
    for (int j = 0; j < 12; ++j) {
      float4 wv = __ldg(w4 + j);
      acc[4 * j + 0] = fmaf(xv, wv.x, acc[4 * j + 0]);
      acc[4 * j + 1] = fmaf(xv, wv.y, acc[4 * j + 1]);
      acc[4 * j + 2] = fmaf(xv, wv.z, acc[4 * j + 2]);
      acc[4 * j + 3] = fmaf(xv, wv.w, acc[4 * j + 3]);
    }
  }
  float* dst = P + ((size_t)(b * Lt + l0 + tok)) * PD + og * 48;
#pragma unroll
  for (int j = 0; j < 48; ++j) {
    int o = og * 48 + j;
    float v = acc[j];
    if (o >= 32 && o < 64) {
      v += dt_b[o - 32];
      v = fmaxf(v, 0.f) + log1pf(__expf(-fabsf(v)));   // softplus
    }
    dst[j] = v;
  }
}

// ---------------- scan phase 1: per-chunk local scan summary ----------------
__global__ __launch_bounds__(256) void k_scan1(const float* __restrict__ P,
    const float* __restrict__ A_log, float* __restrict__ hfin, float* __restrict__ Pc) {
  int b = blockIdx.x & 7, grp = blockIdx.x >> 3;
  int s = RFL(grp * 4 + (threadIdx.x >> 6));
  int r = s >> 4, c = s & 15;
  int n = threadIdx.x & 63;
  float a = -__expf(A_log[r * 64 + n]);
  const float* base = P + ((size_t)(b * Lt + c * CL)) * PD;
  float h = 0.f, sdt = 0.f;
#pragma unroll 4
  for (int t = 0; t < CL; ++t) {
    const float* row = base + t * PD;
    float dt = row[32 + r];
    float u  = row[r];
    float bt = row[64 + n];
    h = fmaf(__expf(dt * a), h, (dt * u) * bt);
    sdt += dt;
  }
  int o = ((b * 32 + r) * 16 + c) * 64 + n;
  hfin[o] = h;
  Pc[o] = __expf(a * sdt);
}

// ---------------- scan phase 2: combine chunk summaries ----------------
__global__ __launch_bounds__(256) void k_scan2(const float* __restrict__ hfin,
    const float* __restrict__ Pc, float* __restrict__ Hs) {
  int wid = blockIdx.x * 4 + (threadIdx.x >> 6);
  int b = wid >> 5, r = wid & 31, n = threadIdx.x & 63;
  float H = 0.f;
  int base = ((b * 32 + r) * 16) * 64 + n;
#pragma unroll
  for (int c = 0; c < 16; ++c) {
    Hs[base + c * 64] = H;
    H = fmaf(Pc[base + c * 64], H, hfin[base + c * 64]);
  }
}

// ---------------- scan phase 3: emit states + y ----------------
__global__ __launch_bounds__(256) void k_scan3(const float* __restrict__ P,
    const float* __restrict__ A_log, const float* __restrict__ Hs,
    const float* __restrict__ Dp, float* __restrict__ states, float* __restrict__ y) {
  __shared__ __align__(16) float ylds[4][32 * 68];
  int b = blockIdx.x & 7, grp = blockIdx.x >> 3;
  int wslot = RFL(threadIdx.x >> 6);
  int s = RFL(grp * 4 + wslot);
  int r = s >> 4, c = s & 15;
  int n = threadIdx.x & 63;
  float a = -__expf(A_log[r * 64 + n]);
  float Dr = Dp[r];
  const float* base = P + ((size_t)(b * Lt + c * CL)) * PD;
  float h = Hs[((b * 32 + r) * 16 + c) * 64 + n];
  float* st = states + ((size_t)(b * Lt + c * CL) * 32 + r) * 64 + n;
  float* yrow = y + (size_t)(b * 32 + r) * Lt + c * CL;
  float* yl = &ylds[wslot][0];
  for (int t0 = 0; t0 < CL; t0 += 32) {
    int BT = min(32, CL - t0);
#pragma unroll 4
    for (int t = t0; t < t0 + BT; ++t) {
      const float* row = base + t * PD;
      float dt = row[32 + r];
      float u  = row[r];
      float bt = row[64 + n];
      float ct = row[128 + n];
      h = fmaf(__expf(dt * a), h, (dt * u) * bt);
      st[(size_t)t * 2048] = h;
      yl[(t - t0) * 68 + n] = h * ct;
    }
    if (n < BT) {
      const float4* rp = (const float4*)(yl + n * 68);
      float s0 = 0.f, s1 = 0.f, s2 = 0.f, s3 = 0.f;
#pragma unroll
      for (int k = 0; k < 16; ++k) {
        float4 pv = rp[k];
        s0 += pv.x; s1 += pv.y; s2 += pv.z; s3 += pv.w;
      }
      float sum = (s0 + s1) + (s2 + s3);
      float uu = base[(size_t)(t0 + n) * PD + r];
      yrow[t0 + n] = sum + Dr * uu;
    }
  }
}

// ---------------- out projection + residual ----------------
__global__ __launch_bounds__(256) void k_outproj(const float* __restrict__ xin,
    const float* __restrict__ y, const float* __restrict__ ow, float* __restrict__ xout) {
  __shared__ float ylds[32 * 64];
  int b = blockIdx.x & 7, tl = blockIdx.x >> 3;
  int l0 = tl * 64;
  int tid = threadIdx.x;
  for (int k = 0; k < 8; ++k) {
    int idx = k * 256 + tid; int r = idx >> 6, li = idx & 63;
    ylds[r * 64 + li] = y[(size_t)(b * 32 + r) * Lt + l0 + li];
  }
  __syncthreads();
  int li = tid & 63, cg = RFL(tid >> 6);
  for (int cc = 0; cc < 16; ++cc) {
    int ci = cg * 16 + cc;
    float acc = xin[(size_t)(b * 64 + ci) * Lt + l0 + li];
    const float4* w4 = (const float4*)(ow + ci * 32);
#pragma unroll
    for (int r4 = 0; r4 < 8; ++r4) {
      float4 wv = __ldg(w4 + r4);
      acc = fmaf(ylds[(r4 * 4 + 0) * 64 + li], wv.x, acc);
      acc = fmaf(ylds[(r4 * 4 + 1) * 64 + li], wv.y, acc);
      acc = fmaf(ylds[(r4 * 4 + 2) * 64 + li], wv.z, acc);
      acc = fmaf(ylds[(r4 * 4 + 3) * 64 + li], wv.w, acc);
    }
    xout[(size_t)(b * 64 + ci) * Lt + l0 + li] = acc;
  }
}

extern "C" void kernel_launch(void* const* d_in, const int* in_sizes, int n_in,
                              void* d_out, int out_size, void* d_ws, size_t ws_size,
                              hipStream_t stream) {
  const float* x      = (const float*)d_in[0];
  const float* stem_w = (const float*)d_in[1];
  const float* stem_g = (const float*)d_in[2];
  const float* stem_b = (const float*)d_in[3];
  const float* stem_m = (const float*)d_in[4];
  const float* stem_v = (const float*)d_in[5];
  const float* in_w   = (const float*)d_in[6];
  const float* dt_w   = (const float*)d_in[7];
  const float* dt_b   = (const float*)d_in[8];
  const float* B_w    = (const float*)d_in[9];
  const float* C_w    = (const float*)d_in[10];
  const float* A_log  = (const float*)d_in[11];
  const float* Dp     = (const float*)d_in[12];
  const float* out_w  = (const float*)d_in[13];
  const float* p4_w   = (const float*)d_in[14];
  const float* p4_g   = (const float*)d_in[15];
  const float* p4_b   = (const float*)d_in[16];
  const float* p4_m   = (const float*)d_in[17];
  const float* p4_v   = (const float*)d_in[18];
  const float* p5_w   = (const float*)d_in[19];
  const float* p5_g   = (const float*)d_in[20];
  const float* p5_b   = (const float*)d_in[21];
  const float* p5_m   = (const float*)d_in[22];
  const float* p5_v   = (const float*)d_in[23];

  float* out = (float*)d_out;
  float* wsf = (float*)d_ws;

  // output regions
  float* p3out = out;                       // 8*64*56*56  = 1605632
  float* p4out = out + 1605632;             // 8*128*28*28 =  802816
  float* p5out = out + 2408448;             // 8*256*14*14 =  401408
  float* stout = out + 2809856;             // 3*8*3136*32*64

  // workspace layout (floats)
  float* x0    = wsf;                  // 1605632
  float* x1    = wsf + 1605632;        // 1605632
  float* Pb    = wsf + 3211264;        // 4816896 (8*3136*192)
  float* yb    = wsf + 8028160;        //  802816 (8*32*3136)
  float* hfin  = wsf + 8830976;        //  262144
  float* Pc    = wsf + 9093120;        //  262144
  float* Hs    = wsf + 9355264;        //  262144
  float* wT    = wsf + 9617408;        //   36864 (3*64*192)
  float* wTs   = wsf + 9654272;        //   18432 (stem 32*9*64)
  float* wT4   = wsf + 9672704;        //   73728 (p4 64*9*128)
  float* wT5   = wsf + 9746432;        //  294912 (p5 128*9*256)
                                       // total 10041344 floats (~40.2 MB)

  k_wtrans<<<144, 256, 0, stream>>>(in_w, dt_w, B_w, C_w, wT);
  k_cwt<<<72, 256, 0, stream>>>(stem_w, wTs, 64, 32);
  k_cwt<<<288, 256, 0, stream>>>(p4_w, wT4, 128, 64);
  k_cwt<<<1152, 256, 0, stream>>>(p5_w, wT5, 256, 128);

  // stem: [8,32,112,112] -> [8,64,56,56]; CPB=64 (lg 6), SPB=4, tiles=8*56*14=6272
  k_conv4<<<1568, 256, 0, stream>>>(x, wTs, stem_g, stem_b, stem_m, stem_v,
                                    x0, 8, 32, 112, 112, 64, 56, 56, 6, 14);

  const float* xi = x0;
  for (int i = 0; i < 3; ++i) {
    k_proj<<<392, 256, 0, stream>>>(xi, wT + i * 64 * PD, dt_b + i * 32, Pb);
    k_scan1<<<1024, 256, 0, stream>>>(Pb, A_log + i * 2048, hfin, Pc);
    k_scan2<<<64, 256, 0, stream>>>(hfin, Pc, Hs);
    k_scan3<<<1024, 256, 0, stream>>>(Pb, A_log + i * 2048, Hs, Dp + i * 32,
                                      stout + (size_t)i * 51380224, yb);
    float* dst = (i == 2) ? p3out : ((i == 0) ? x1 : x0);
    k_outproj<<<392, 256, 0, stream>>>(xi, yb, out_w + i * 2048, dst);
    xi = dst;
  }

  // p4: [8,64,56,56] -> [8,128,28,28]; CPB=128 (lg 7), SPB=2, tiles=8*28*7=1568
  k_conv4<<<784, 256, 0, stream>>>(p3out, wT4, p4_g, p4_b, p4_m, p4_v,
                                   p4out, 8, 64, 56, 56, 128, 28, 28, 7, 7);
  // p5: [8,128,28,28] -> [8,256,14,14]; CPB=256 (lg 8), SPB=1, tiles=8*14*4=448
  k_conv4<<<448, 256, 0, stream>>>(p4out, wT5, p5_g, p5_b, p5_m, p5_v,
                                   p5out, 8, 128, 28, 28, 256, 14, 14, 8, 4);
}

// Round 3
// 575.805 us; speedup vs baseline: 2.5271x; 1.3540x over previous
//
#include <hip/hip_runtime.h>
#include <cstdint>
#include <cstddef>

#define RFL(x) __builtin_amdgcn_readfirstlane(x)

constexpr int E  = 64;     // channels in SS2D stage
constexpr int Rr = 32;     // low rank
constexpr int Nn = 64;     // state dim
constexpr int Lt = 3136;   // 56*56 tokens
constexpr int NC = 28;     // scan chunks
constexpr int CL = 112;    // Lt/NC
constexpr int PD = 192;    // packed proj row: [u(32) | dt(32) | B(64) | C(64)]

// ---------------- SS2D weight transpose: wT[i][c][o] ----------------
__global__ __launch_bounds__(256) void k_wtrans(const float* __restrict__ in_w,
    const float* __restrict__ dt_w, const float* __restrict__ B_w,
    const float* __restrict__ C_w, float* __restrict__ wT) {
  int idx = blockIdx.x * 256 + threadIdx.x;
  if (idx >= 3 * 64 * PD) return;
  int o = idx % PD; int c = (idx / PD) & 63; int i = idx / (PD * 64);
  float v;
  if (o < 32)       v = in_w[(i * 32 + o) * 64 + c];
  else if (o < 64)  v = dt_w[(i * 32 + (o - 32)) * 64 + c];
  else if (o < 128) v = B_w[(i * 64 + (o - 64)) * 64 + c];
  else              v = C_w[(i * 64 + (o - 128)) * 64 + c];
  wT[idx] = v;
}

// ---------------- conv weight repack: w[Cout][Cin][9] -> w2[Cin][Cout][12] ----------------
__global__ __launch_bounds__(256) void k_cwt(const float* __restrict__ w,
    float* __restrict__ w2, int Cout, int Cin) {
  int idx = blockIdx.x * 256 + threadIdx.x;
  if (idx >= Cin * Cout * 12) return;
  int k = idx % 12; int co = (idx / 12) % Cout; int ci = idx / (12 * Cout);
  w2[idx] = (k < 9) ? w[((size_t)co * Cin + ci) * 9 + k] : 0.f;
}

// ---------------- conv3x3 s2 p1 + BN + SiLU, LDS-staged, compile-time dims ----------------
// co-per-lane compute; x tile in LDS (broadcast reads); output transposed via LDS for
// ow-contiguous stores. Block = 256 thr = CPB co-lanes x SLOTS ow-segments of OWT.
template<int CIN, int COUT, int HIN, int WIN, int CPB, int OWT, int CIB>
__global__ __launch_bounds__(256) void k_conv(const float* __restrict__ x,
    const float* __restrict__ w2, const float* __restrict__ g, const float* __restrict__ bb,
    const float* __restrict__ m, const float* __restrict__ vv, float* __restrict__ out) {
  constexpr int HOUT = HIN / 2, WOUT = WIN / 2;
  constexpr int SLOTS = 256 / CPB;
  constexpr int SPAN = SLOTS * OWT;
  constexpr int GWX = (WOUT + SPAN - 1) / SPAN;
  constexpr int COG = COUT / CPB;
  constexpr int INSP = 2 * SPAN + 2;
  constexpr int LDSW = (INSP + 3) & ~3;
  constexpr int CHUNKS = CIN / CIB;
  __shared__ float xs[CIB][3][LDSW];
  __shared__ float tbuf[CPB][SPAN + 1];

  int t = blockIdx.x;
  int b = t & 7; t >>= 3;
  int oh = t % HOUT; t /= HOUT;
  int gx = t % GWX; int cog = t / GWX;
  int col = threadIdx.x & (CPB - 1);
  int co = col + cog * CPB;
  int slot = threadIdx.x / CPB;          // wave-uniform (CPB >= 64)
  int iwb = gx * SPAN * 2;               // lds col d <-> iw = iwb + d - 1
  int ih0 = oh * 2 - 1;

  float acc[OWT];
#pragma unroll
  for (int o = 0; o < OWT; ++o) acc[o] = 0.f;

  for (int ch = 0; ch < CHUNKS; ++ch) {
    if (ch) __syncthreads();
    for (int i = threadIdx.x; i < CIB * 3 * LDSW; i += 256) {
      int d = i % LDSW; int rr = (i / LDSW) % 3; int cc = i / (3 * LDSW);
      int iw = iwb + d - 1; int ih = ih0 + rr;
      float v = 0.f;
      if (d < INSP && (unsigned)iw < (unsigned)WIN && (unsigned)ih < (unsigned)HIN)
        v = x[(((size_t)(b * CIN + ch * CIB + cc)) * HIN + ih) * WIN + iw];
      xs[cc][rr][d] = v;
    }
    __syncthreads();
    const float* wp = w2 + ((size_t)(ch * CIB) * COUT + co) * 12;
#pragma unroll 2
    for (int ci = 0; ci < CIB; ++ci) {
      const float* wr = wp + (size_t)ci * COUT * 12;
      float4 wa = *(const float4*)(wr);
      float4 wb = *(const float4*)(wr + 4);
      float  wc = wr[8];
      float wk[9] = {wa.x, wa.y, wa.z, wa.w, wb.x, wb.y, wb.z, wb.w, wc};
#pragma unroll
      for (int kh = 0; kh < 3; ++kh) {
        const float2* tp2 = (const float2*)(&xs[ci][kh][slot * OWT * 2]);
        float tp[2 * OWT + 2];
#pragma unroll
        for (int j = 0; j < OWT + 1; ++j) { float2 v = tp2[j]; tp[2*j] = v.x; tp[2*j+1] = v.y; }
#pragma unroll
        for (int o = 0; o < OWT; ++o) {
          acc[o] = fmaf(tp[2*o],     wk[kh*3+0], acc[o]);
          acc[o] = fmaf(tp[2*o + 1], wk[kh*3+1], acc[o]);
          acc[o] = fmaf(tp[2*o + 2], wk[kh*3+2], acc[o]);
        }
      }
    }
  }

  float scale = g[co] * rsqrtf(vv[co] + 1e-5f);
  float mb = m[co], bc = bb[co];
#pragma unroll
  for (int o = 0; o < OWT; ++o) {
    float yv = (acc[o] - mb) * scale + bc;
    tbuf[col][slot * OWT + o] = yv / (1.f + __expf(-yv));
  }
  __syncthreads();
  for (int i = threadIdx.x; i < CPB * SPAN; i += 256) {
    int owl = i % SPAN; int cl = i / SPAN;
    int ow = gx * SPAN + owl;
    if (ow < WOUT)
      out[(((size_t)(b * COUT + cog * CPB + cl)) * HOUT + oh) * WOUT + ow] = tbuf[cl][owl];
  }
}

// ---------------- token projections: x[b][c][l] -> P[b][l][192] ----------------
__global__ __launch_bounds__(256) void k_proj(const float* __restrict__ xin,
    const float* __restrict__ wT, const float* __restrict__ dt_b, float* __restrict__ P) {
  int b = blockIdx.x & 7, tl = blockIdx.x >> 3;
  int l0 = tl * 64;
  __shared__ float xl[64 * 65];
  int tid = threadIdx.x;
  for (int k = 0; k < 16; ++k) {
    int idx = k * 256 + tid; int c = idx >> 6, li = idx & 63;
    xl[c * 65 + li] = xin[(size_t)(b * 64 + c) * Lt + l0 + li];
  }
  __syncthreads();
  int tok = tid & 63;
  int og = RFL(tid >> 6);
  const float* wbase = wT + og * 48;
  float acc[48];
#pragma unroll
  for (int j = 0; j < 48; ++j) acc[j] = 0.f;
  for (int c = 0; c < 64; ++c) {
    float xv = xl[c * 65 + tok];
    const float4* w4 = (const float4*)(wbase + c * PD);
#pragma unroll
    for (int j = 0; j < 12; ++j) {
      float4 wv = __ldg(w4 + j);
      acc[4 * j + 0] = fmaf(xv, wv.x, acc[4 * j + 0]);
      acc[4 * j + 1] = fmaf(xv, wv.y, acc[4 * j + 1]);
      acc[4 * j + 2] = fmaf(xv, wv.z, acc[4 * j + 2]);
      acc[4 * j + 3] = fmaf(xv, wv.w, acc[4 * j + 3]);
    }
  }
  float* dst = P + ((size_t)(b * Lt + l0 + tok)) * PD + og * 48;
#pragma unroll
  for (int j = 0; j < 48; ++j) {
    int o = og * 48 + j;
    float v = acc[j];
    if (o >= 32 && o < 64) {
      v += dt_b[o - 32];
      v = fmaxf(v, 0.f) + log1pf(__expf(-fabsf(v)));   // softplus
    }
    dst[j] = v;
  }
}

// ---------------- scan phase 1: per-chunk local scan summary ----------------
__global__ __launch_bounds__(256) void k_scan1(const float* __restrict__ P,
    const float* __restrict__ A_log, float* __restrict__ hfin, float* __restrict__ Pc) {
  int b = blockIdx.x & 7, grp = blockIdx.x >> 3;     // grp in [0,224)
  int s = RFL(grp * 4 + (threadIdx.x >> 6));         // 0..895
  int r = s / NC, c = s % NC;
  int n = threadIdx.x & 63;
  float a = -__expf(A_log[r * 64 + n]);
  const float* base = P + ((size_t)(b * Lt + c * CL)) * PD;
  float h = 0.f, sdt = 0.f;
#pragma unroll 4
  for (int t = 0; t < CL; ++t) {
    const float* row = base + t * PD;
    float dt = row[32 + r];
    float u  = row[r];
    float bt = row[64 + n];
    h = fmaf(__expf(dt * a), h, (dt * u) * bt);
    sdt += dt;
  }
  int o = ((b * 32 + r) * NC + c) * 64 + n;
  hfin[o] = h;
  Pc[o] = __expf(a * sdt);
}

// ---------------- scan phase 2: combine chunk summaries ----------------
__global__ __launch_bounds__(256) void k_scan2(const float* __restrict__ hfin,
    const float* __restrict__ Pc, float* __restrict__ Hs) {
  int wid = blockIdx.x * 4 + (threadIdx.x >> 6);
  int b = wid >> 5, r = wid & 31, n = threadIdx.x & 63;
  float H = 0.f;
  int base = ((b * 32 + r) * NC) * 64 + n;
#pragma unroll
  for (int c = 0; c < NC; ++c) {
    Hs[base + c * 64] = H;
    H = fmaf(Pc[base + c * 64], H, hfin[base + c * 64]);
  }
}

// ---------------- scan phase 3: emit states + y ----------------
__global__ __launch_bounds__(256) void k_scan3(const float* __restrict__ P,
    const float* __restrict__ A_log, const float* __restrict__ Hs,
    const float* __restrict__ Dp, float* __restrict__ states, float* __restrict__ y) {
  __shared__ __align__(16) float ylds[4][32 * 68];
  int b = blockIdx.x & 7, grp = blockIdx.x >> 3;
  int wslot = RFL(threadIdx.x >> 6);
  int s = RFL(grp * 4 + wslot);
  int r = s / NC, c = s % NC;
  int n = threadIdx.x & 63;
  float a = -__expf(A_log[r * 64 + n]);
  float Dr = Dp[r];
  const float* base = P + ((size_t)(b * Lt + c * CL)) * PD;
  float h = Hs[((b * 32 + r) * NC + c) * 64 + n];
  float* st = states + ((size_t)(b * Lt + c * CL) * 32 + r) * 64 + n;
  float* yrow = y + (size_t)(b * 32 + r) * Lt + c * CL;
  float* yl = &ylds[wslot][0];
  for (int t0 = 0; t0 < CL; t0 += 32) {
    int BT = min(32, CL - t0);
#pragma unroll 4
    for (int t = t0; t < t0 + BT; ++t) {
      const float* row = base + t * PD;
      float dt = row[32 + r];
      float u  = row[r];
      float bt = row[64 + n];
      float ct = row[128 + n];
      h = fmaf(__expf(dt * a), h, (dt * u) * bt);
      st[(size_t)t * 2048] = h;
      yl[(t - t0) * 68 + n] = h * ct;
    }
    if (n < BT) {
      const float4* rp = (const float4*)(yl + n * 68);
      float s0 = 0.f, s1 = 0.f, s2 = 0.f, s3 = 0.f;
#pragma unroll
      for (int k = 0; k < 16; ++k) {
        float4 pv = rp[k];
        s0 += pv.x; s1 += pv.y; s2 += pv.z; s3 += pv.w;
      }
      float sum = (s0 + s1) + (s2 + s3);
      float uu = base[(size_t)(t0 + n) * PD + r];
      yrow[t0 + n] = sum + Dr * uu;
    }
  }
}

// ---------------- out projection + residual ----------------
__global__ __launch_bounds__(256) void k_outproj(const float* __restrict__ xin,
    const float* __restrict__ y, const float* __restrict__ ow, float* __restrict__ xout) {
  __shared__ float ylds[32 * 64];
  int b = blockIdx.x & 7, tl = blockIdx.x >> 3;
  int l0 = tl * 64;
  int tid = threadIdx.x;
  for (int k = 0; k < 8; ++k) {
    int idx = k * 256 + tid; int r = idx >> 6, li = idx & 63;
    ylds[r * 64 + li] = y[(size_t)(b * 32 + r) * Lt + l0 + li];
  }
  __syncthreads();
  int li = tid & 63, cg = RFL(tid >> 6);
  for (int cc = 0; cc < 16; ++cc) {
    int ci = cg * 16 + cc;
    float acc = xin[(size_t)(b * 64 + ci) * Lt + l0 + li];
    const float4* w4 = (const float4*)(ow + ci * 32);
#pragma unroll
    for (int r4 = 0; r4 < 8; ++r4) {
      float4 wv = __ldg(w4 + r4);
      acc = fmaf(ylds[(r4 * 4 + 0) * 64 + li], wv.x, acc);
      acc = fmaf(ylds[(r4 * 4 + 1) * 64 + li], wv.y, acc);
      acc = fmaf(ylds[(r4 * 4 + 2) * 64 + li], wv.z, acc);
      acc = fmaf(ylds[(r4 * 4 + 3) * 64 + li], wv.w, acc);
    }
    xout[(size_t)(b * 64 + ci) * Lt + l0 + li] = acc;
  }
}

extern "C" void kernel_launch(void* const* d_in, const int* in_sizes, int n_in,
                              void* d_out, int out_size, void* d_ws, size_t ws_size,
                              hipStream_t stream) {
  const float* x      = (const float*)d_in[0];
  const float* stem_w = (const float*)d_in[1];
  const float* stem_g = (const float*)d_in[2];
  const float* stem_b = (const float*)d_in[3];
  const float* stem_m = (const float*)d_in[4];
  const float* stem_v = (const float*)d_in[5];
  const float* in_w   = (const float*)d_in[6];
  const float* dt_w   = (const float*)d_in[7];
  const float* dt_b   = (const float*)d_in[8];
  const float* B_w    = (const float*)d_in[9];
  const float* C_w    = (const float*)d_in[10];
  const float* A_log  = (const float*)d_in[11];
  const float* Dp     = (const float*)d_in[12];
  const float* out_w  = (const float*)d_in[13];
  const float* p4_w   = (const float*)d_in[14];
  const float* p4_g   = (const float*)d_in[15];
  const float* p4_b   = (const float*)d_in[16];
  const float* p4_m   = (const float*)d_in[17];
  const float* p4_v   = (const float*)d_in[18];
  const float* p5_w   = (const float*)d_in[19];
  const float* p5_g   = (const float*)d_in[20];
  const float* p5_b   = (const float*)d_in[21];
  const float* p5_m   = (const float*)d_in[22];
  const float* p5_v   = (const float*)d_in[23];

  float* out = (float*)d_out;
  float* wsf = (float*)d_ws;

  // output regions
  float* p3out = out;                       // 8*64*56*56  = 1605632
  float* p4out = out + 1605632;             // 8*128*28*28 =  802816
  float* p5out = out + 2408448;             // 8*256*14*14 =  401408
  float* stout = out + 2809856;             // 3*8*3136*32*64

  // workspace layout (floats) ~43.0 MB
  float* x0    = wsf;                   // 1605632
  float* x1    = wsf + 1605632;         // 1605632
  float* Pb    = wsf + 3211264;         // 4816896 (8*3136*192)
  float* yb    = wsf + 8028160;         //  802816 (8*32*3136)
  float* hfin  = wsf + 8830976;         //  458752 (8*32*28*64)
  float* Pc    = wsf + 9289728;         //  458752
  float* Hs    = wsf + 9748480;         //  458752
  float* wT    = wsf + 10207232;        //   36864 (3*64*192)
  float* wTs   = wsf + 10244096;        //   24576 (stem 32*64*12)
  float* wT4   = wsf + 10268672;        //   98304 (p4 64*128*12)
  float* wT5   = wsf + 10366976;        //  393216 (p5 128*256*12)

  k_wtrans<<<144, 256, 0, stream>>>(in_w, dt_w, B_w, C_w, wT);
  k_cwt<<<96, 256, 0, stream>>>(stem_w, wTs, 64, 32);
  k_cwt<<<384, 256, 0, stream>>>(p4_w, wT4, 128, 64);
  k_cwt<<<1536, 256, 0, stream>>>(p5_w, wT5, 256, 128);

  // stem: [8,32,112,112] -> [8,64,56,56]; CPB=64, OWT=7 (SPAN 28, GWX 2) -> 896 blocks
  k_conv<32, 64, 112, 112, 64, 7, 16><<<896, 256, 0, stream>>>(
      x, wTs, stem_g, stem_b, stem_m, stem_v, x0);

  const float* xi = x0;
  for (int i = 0; i < 3; ++i) {
    k_proj<<<392, 256, 0, stream>>>(xi, wT + i * 64 * PD, dt_b + i * 32, Pb);
    k_scan1<<<1792, 256, 0, stream>>>(Pb, A_log + i * 2048, hfin, Pc);
    k_scan2<<<64, 256, 0, stream>>>(hfin, Pc, Hs);
    k_scan3<<<1792, 256, 0, stream>>>(Pb, A_log + i * 2048, Hs, Dp + i * 32,
                                      stout + (size_t)i * 51380224, yb);
    float* dst = (i == 2) ? p3out : ((i == 0) ? x1 : x0);
    k_outproj<<<392, 256, 0, stream>>>(xi, yb, out_w + i * 2048, dst);
    xi = dst;
  }

  // p4: [8,64,56,56] -> [8,128,28,28]; CPB=128, OWT=4 (SPAN 8, GWX 4) -> 896 blocks
  k_conv<64, 128, 56, 56, 128, 4, 32><<<896, 256, 0, stream>>>(
      p3out, wT4, p4_g, p4_b, p4_m, p4_v, p4out);
  // p5: [8,128,28,28] -> [8,256,14,14]; CPB=128, OWT=2 (SPAN 4, GWX 4, COG 2) -> 896 blocks
  k_conv<128, 256, 28, 28, 128, 2, 64><<<896, 256, 0, stream>>>(
      p4out, wT5, p5_g, p5_b, p5_m, p5_v, p5out);
}

// Round 4
// 524.851 us; speedup vs baseline: 2.7724x; 1.0971x over previous
//
#include <hip/hip_runtime.h>
#include <cstdint>
#include <cstddef>

#define RFL(x) __builtin_amdgcn_readfirstlane(x)

constexpr int E  = 64;     // channels in SS2D stage
constexpr int Rr = 32;     // low rank
constexpr int Nn = 64;     // state dim
constexpr int Lt = 3136;   // 56*56 tokens
constexpr int NC = 28;     // scan chunks
constexpr int CL = 112;    // Lt/NC
constexpr int PD = 192;    // packed proj row: [u(32) | dt(32) | B(64) | C(64)]

// ---------------- SS2D weight transpose: wT[i][c][o] ----------------
__global__ __launch_bounds__(256) void k_wtrans(const float* __restrict__ in_w,
    const float* __restrict__ dt_w, const float* __restrict__ B_w,
    const float* __restrict__ C_w, float* __restrict__ wT) {
  int idx = blockIdx.x * 256 + threadIdx.x;
  if (idx >= 3 * 64 * PD) return;
  int o = idx % PD; int c = (idx / PD) & 63; int i = idx / (PD * 64);
  float v;
  if (o < 32)       v = in_w[(i * 32 + o) * 64 + c];
  else if (o < 64)  v = dt_w[(i * 32 + (o - 32)) * 64 + c];
  else if (o < 128) v = B_w[(i * 64 + (o - 64)) * 64 + c];
  else              v = C_w[(i * 64 + (o - 128)) * 64 + c];
  wT[idx] = v;
}

// ---------------- conv weight repack: w[Cout][Cin][9] -> w3[Cin][9][Cout] ----------------
__global__ __launch_bounds__(256) void k_cwt2(const float* __restrict__ w,
    float* __restrict__ w3, int Cout, int Cin) {
  int idx = blockIdx.x * 256 + threadIdx.x;
  if (idx >= Cin * Cout * 9) return;
  int co = idx % Cout; int k = (idx / Cout) % 9; int ci = idx / (9 * Cout);
  w3[idx] = w[((size_t)co * Cin + ci) * 9 + k];
}

// ---------------- conv3x3 s2 p1 + BN + SiLU ----------------
// co-per-lane (64 lanes = 64 co of this cog); x tile LDS-staged (broadcast reads);
// weights [ci][k][co] -> coalesced 256B wave loads; LDS output transpose for stores.
template<int CIN, int COUT, int HIN, int WIN, int OWT, int CIB>
__global__ __launch_bounds__(256) void k_conv(const float* __restrict__ x,
    const float* __restrict__ w3, const float* __restrict__ g, const float* __restrict__ bb,
    const float* __restrict__ m, const float* __restrict__ vv, float* __restrict__ out) {
  constexpr int HOUT = HIN / 2, WOUT = WIN / 2;
  constexpr int SPAN = 4 * OWT;
  constexpr int GWX = (WOUT + SPAN - 1) / SPAN;
  constexpr int COG = COUT / 64;
  constexpr int INSP = 2 * SPAN + 2;
  constexpr int LDSW = (INSP + 3) & ~3;
  constexpr int CHUNKS = CIN / CIB;
  __shared__ float xs[CIB][3][LDSW];
  __shared__ float tbuf[64][SPAN + 1];

  int t = blockIdx.x;
  int b = t & 7; t >>= 3;
  int oh = t % HOUT; t /= HOUT;
  int gx = t % GWX; int cog = t / GWX;
  int lane = threadIdx.x & 63;
  int co = cog * 64 + lane;
  int slot = threadIdx.x >> 6;           // wave id, uniform
  int iwb = gx * SPAN * 2;               // lds col d <-> iw = iwb + d - 1
  int ih0 = oh * 2 - 1;

  float acc[OWT];
#pragma unroll
  for (int o = 0; o < OWT; ++o) acc[o] = 0.f;

  for (int ch = 0; ch < CHUNKS; ++ch) {
    if (ch) __syncthreads();
    for (int i = threadIdx.x; i < CIB * 3 * LDSW; i += 256) {
      int d = i % LDSW; int rr = (i / LDSW) % 3; int cc = i / (3 * LDSW);
      int iw = iwb + d - 1; int ih = ih0 + rr;
      float v = 0.f;
      if (d < INSP && (unsigned)iw < (unsigned)WIN && (unsigned)ih < (unsigned)HIN)
        v = x[(((size_t)(b * CIN + ch * CIB + cc)) * HIN + ih) * WIN + iw];
      xs[cc][rr][d] = v;
    }
    __syncthreads();
#pragma unroll 2
    for (int ci = 0; ci < CIB; ++ci) {
      const float* wr = w3 + ((size_t)((ch * CIB + ci) * 9)) * COUT + co;
      float wk[9];
#pragma unroll
      for (int k = 0; k < 9; ++k) wk[k] = wr[(size_t)k * COUT];
#pragma unroll
      for (int kh = 0; kh < 3; ++kh) {
        const float2* tp2 = (const float2*)(&xs[ci][kh][slot * OWT * 2]);
        float tp[2 * OWT + 2];
#pragma unroll
        for (int j = 0; j < OWT + 1; ++j) { float2 v = tp2[j]; tp[2*j] = v.x; tp[2*j+1] = v.y; }
#pragma unroll
        for (int o = 0; o < OWT; ++o) {
          acc[o] = fmaf(tp[2*o],     wk[kh*3+0], acc[o]);
          acc[o] = fmaf(tp[2*o + 1], wk[kh*3+1], acc[o]);
          acc[o] = fmaf(tp[2*o + 2], wk[kh*3+2], acc[o]);
        }
      }
    }
  }

  float scale = g[co] * rsqrtf(vv[co] + 1e-5f);
  float mb = m[co], bc = bb[co];
#pragma unroll
  for (int o = 0; o < OWT; ++o) {
    float yv = (acc[o] - mb) * scale + bc;
    tbuf[lane][slot * OWT + o] = yv / (1.f + __expf(-yv));
  }
  __syncthreads();
  for (int i = threadIdx.x; i < 64 * SPAN; i += 256) {
    int owl = i % SPAN; int cl = i / SPAN;
    int ow = gx * SPAN + owl;
    if (ow < WOUT)
      out[(((size_t)(b * COUT + cog * 64 + cl)) * HOUT + oh) * WOUT + ow] = tbuf[cl][owl];
  }
}

// ---------------- token projections: x[b][c][l] -> P[b][l][192], LDS-staged stores ----------------
__global__ __launch_bounds__(256) void k_proj(const float* __restrict__ xin,
    const float* __restrict__ wT, const float* __restrict__ dt_b, float* __restrict__ P) {
  __shared__ float sm[64 * 196];          // phase A: xl[64][65]; phase B: out[64 tok][196 pad]
  int b = blockIdx.x & 7, tl = blockIdx.x >> 3;
  int l0 = tl * 64;
  int tid = threadIdx.x;
  for (int k = 0; k < 16; ++k) {
    int idx = k * 256 + tid; int c = idx >> 6, li = idx & 63;
    sm[c * 65 + li] = xin[(size_t)(b * 64 + c) * Lt + l0 + li];
  }
  __syncthreads();
  int tok = tid & 63;
  int og = RFL(tid >> 6);
  const float* wbase = wT + og * 48;
  float acc[48];
#pragma unroll
  for (int j = 0; j < 48; ++j) acc[j] = 0.f;
  for (int c = 0; c < 64; ++c) {
    float xv = sm[c * 65 + tok];
    const float4* w4 = (const float4*)(wbase + c * PD);
#pragma unroll
    for (int j = 0; j < 12; ++j) {
      float4 wv = __ldg(w4 + j);
      acc[4 * j + 0] = fmaf(xv, wv.x, acc[4 * j + 0]);
      acc[4 * j + 1] = fmaf(xv, wv.y, acc[4 * j + 1]);
      acc[4 * j + 2] = fmaf(xv, wv.z, acc[4 * j + 2]);
      acc[4 * j + 3] = fmaf(xv, wv.w, acc[4 * j + 3]);
    }
  }
  __syncthreads();                         // xl dead; reuse sm for output staging
#pragma unroll
  for (int j = 0; j < 48; ++j) {
    int o = og * 48 + j;
    float v = acc[j];
    if (o >= 32 && o < 64) {
      v += dt_b[o - 32];
      v = fmaxf(v, 0.f) + log1pf(__expf(-fabsf(v)));   // softplus
    }
    sm[tok * 196 + o] = v;
  }
  __syncthreads();
  float* dst = P + ((size_t)(b * Lt + l0)) * PD;       // 12288 contiguous floats
#pragma unroll
  for (int it = 0; it < 12; ++it) {
    int f = it * 1024 + tid * 4;
    int tk = f / 192;
    float4 v = *(const float4*)(&sm[tk * 196 + (f - tk * 192)]);
    *(float4*)(dst + f) = v;
  }
}

// ---------------- scan phase 1: per-chunk local scan summary (P LDS-staged) ----------------
__global__ __launch_bounds__(256) void k_scan1(const float* __restrict__ P,
    const float* __restrict__ A_log, float* __restrict__ hfin, float* __restrict__ Pc) {
  __shared__ float xl[16][132];
  int bid = blockIdx.x;
  int b = bid & 7; int rest = bid >> 3;
  int c = rest % NC; int rg = rest / NC;      // rg 0..7
  int ws = RFL(threadIdx.x >> 6);
  int r = rg * 4 + ws;
  int n = threadIdx.x & 63;
  float a = -__expf(A_log[r * 64 + n]);
  const float* base = P + ((size_t)(b * Lt + c * CL)) * PD;
  int tl = threadIdx.x >> 4;                  // 0..15
  int colb = (threadIdx.x & 15) * 8;          // 0..120
  float h = 0.f, sdt = 0.f;
  for (int s0 = 0; s0 < CL; s0 += 16) {
    __syncthreads();
    const float4* src = (const float4*)(base + (size_t)(s0 + tl) * PD + colb);
    float4 v0 = src[0], v1 = src[1];
    *(float4*)(&xl[tl][colb]) = v0;
    *(float4*)(&xl[tl][colb + 4]) = v1;
    __syncthreads();
#pragma unroll
    for (int tt = 0; tt < 16; ++tt) {
      float dt = xl[tt][32 + r];
      float u  = xl[tt][r];
      float bt = xl[tt][64 + n];
      h = fmaf(__expf(dt * a), h, (dt * u) * bt);
      sdt += dt;
    }
  }
  int o = ((b * 32 + r) * NC + c) * 64 + n;
  hfin[o] = h;
  Pc[o] = __expf(a * sdt);
}

// ---------------- scan phase 2: combine chunk summaries ----------------
__global__ __launch_bounds__(256) void k_scan2(const float* __restrict__ hfin,
    const float* __restrict__ Pc, float* __restrict__ Hs) {
  int wid = blockIdx.x * 4 + (threadIdx.x >> 6);
  int b = wid >> 5, r = wid & 31, n = threadIdx.x & 63;
  float H = 0.f;
  int base = ((b * 32 + r) * NC) * 64 + n;
#pragma unroll
  for (int c = 0; c < NC; ++c) {
    Hs[base + c * 64] = H;
    H = fmaf(Pc[base + c * 64], H, hfin[base + c * 64]);
  }
}

// ---------------- scan phase 3: emit states + y (P LDS-staged) ----------------
__global__ __launch_bounds__(256) void k_scan3(const float* __restrict__ P,
    const float* __restrict__ A_log, const float* __restrict__ Hs,
    const float* __restrict__ Dp, float* __restrict__ states, float* __restrict__ y) {
  __shared__ float xl[16][196];
  __shared__ __align__(16) float ylds[4][16][68];
  int bid = blockIdx.x;
  int b = bid & 7; int rest = bid >> 3;
  int c = rest % NC; int rg = rest / NC;
  int ws = RFL(threadIdx.x >> 6);
  int r = rg * 4 + ws;
  int n = threadIdx.x & 63;
  float a = -__expf(A_log[r * 64 + n]);
  float Dr = Dp[r];
  const float* base = P + ((size_t)(b * Lt + c * CL)) * PD;
  float h = Hs[((b * 32 + r) * NC + c) * 64 + n];
  float* st = states + ((size_t)(b * Lt + c * CL) * 32 + r) * 64 + n;
  float* yrow = y + (size_t)(b * 32 + r) * Lt + c * CL;
  int tl = threadIdx.x >> 4;
  int colb = (threadIdx.x & 15) * 12;         // 0..180
  for (int s0 = 0; s0 < CL; s0 += 16) {
    __syncthreads();
    const float4* src = (const float4*)(base + (size_t)(s0 + tl) * PD + colb);
    float4 v0 = src[0], v1 = src[1], v2 = src[2];
    *(float4*)(&xl[tl][colb])     = v0;
    *(float4*)(&xl[tl][colb + 4]) = v1;
    *(float4*)(&xl[tl][colb + 8]) = v2;
    __syncthreads();
#pragma unroll
    for (int tt = 0; tt < 16; ++tt) {
      float dt = xl[tt][32 + r];
      float u  = xl[tt][r];
      float bt = xl[tt][64 + n];
      float ct = xl[tt][128 + n];
      h = fmaf(__expf(dt * a), h, (dt * u) * bt);
      st[(size_t)(s0 + tt) * 2048] = h;
      ylds[ws][tt][n] = h * ct;
    }
    if (n < 16) {
      const float4* rp = (const float4*)(&ylds[ws][n][0]);
      float a0 = 0.f, a1 = 0.f, a2 = 0.f, a3 = 0.f;
#pragma unroll
      for (int k = 0; k < 16; ++k) {
        float4 pv = rp[k];
        a0 += pv.x; a1 += pv.y; a2 += pv.z; a3 += pv.w;
      }
      float sum = (a0 + a1) + (a2 + a3);
      float uu = xl[n][r];
      yrow[s0 + n] = sum + Dr * uu;
    }
  }
}

// ---------------- out projection + residual ----------------
__global__ __launch_bounds__(256) void k_outproj(const float* __restrict__ xin,
    const float* __restrict__ y, const float* __restrict__ ow, float* __restrict__ xout) {
  __shared__ float ylds[32 * 64];
  int b = blockIdx.x & 7, tl = blockIdx.x >> 3;
  int l0 = tl * 64;
  int tid = threadIdx.x;
  for (int k = 0; k < 8; ++k) {
    int idx = k * 256 + tid; int r = idx >> 6, li = idx & 63;
    ylds[r * 64 + li] = y[(size_t)(b * 32 + r) * Lt + l0 + li];
  }
  __syncthreads();
  int li = tid & 63, cg = RFL(tid >> 6);
  for (int cc = 0; cc < 16; ++cc) {
    int ci = cg * 16 + cc;
    float acc = xin[(size_t)(b * 64 + ci) * Lt + l0 + li];
    const float4* w4 = (const float4*)(ow + ci * 32);
#pragma unroll
    for (int r4 = 0; r4 < 8; ++r4) {
      float4 wv = __ldg(w4 + r4);
      acc = fmaf(ylds[(r4 * 4 + 0) * 64 + li], wv.x, acc);
      acc = fmaf(ylds[(r4 * 4 + 1) * 64 + li], wv.y, acc);
      acc = fmaf(ylds[(r4 * 4 + 2) * 64 + li], wv.z, acc);
      acc = fmaf(ylds[(r4 * 4 + 3) * 64 + li], wv.w, acc);
    }
    xout[(size_t)(b * 64 + ci) * Lt + l0 + li] = acc;
  }
}

extern "C" void kernel_launch(void* const* d_in, const int* in_sizes, int n_in,
                              void* d_out, int out_size, void* d_ws, size_t ws_size,
                              hipStream_t stream) {
  const float* x      = (const float*)d_in[0];
  const float* stem_w = (const float*)d_in[1];
  const float* stem_g = (const float*)d_in[2];
  const float* stem_b = (const float*)d_in[3];
  const float* stem_m = (const float*)d_in[4];
  const float* stem_v = (const float*)d_in[5];
  const float* in_w   = (const float*)d_in[6];
  const float* dt_w   = (const float*)d_in[7];
  const float* dt_b   = (const float*)d_in[8];
  const float* B_w    = (const float*)d_in[9];
  const float* C_w    = (const float*)d_in[10];
  const float* A_log  = (const float*)d_in[11];
  const float* Dp     = (const float*)d_in[12];
  const float* out_w  = (const float*)d_in[13];
  const float* p4_w   = (const float*)d_in[14];
  const float* p4_g   = (const float*)d_in[15];
  const float* p4_b   = (const float*)d_in[16];
  const float* p4_m   = (const float*)d_in[17];
  const float* p4_v   = (const float*)d_in[18];
  const float* p5_w   = (const float*)d_in[19];
  const float* p5_g   = (const float*)d_in[20];
  const float* p5_b   = (const float*)d_in[21];
  const float* p5_m   = (const float*)d_in[22];
  const float* p5_v   = (const float*)d_in[23];

  float* out = (float*)d_out;
  float* wsf = (float*)d_ws;

  // output regions
  float* p3out = out;                       // 8*64*56*56  = 1605632
  float* p4out = out + 1605632;             // 8*128*28*28 =  802816
  float* p5out = out + 2408448;             // 8*256*14*14 =  401408
  float* stout = out + 2809856;             // 3*8*3136*32*64

  // workspace layout (floats) ~42.5 MB
  float* x0    = wsf;                   // 1605632
  float* x1    = wsf + 1605632;         // 1605632
  float* Pb    = wsf + 3211264;         // 4816896 (8*3136*192)
  float* yb    = wsf + 8028160;         //  802816 (8*32*3136)
  float* hfin  = wsf + 8830976;         //  458752 (8*32*28*64)
  float* Pc    = wsf + 9289728;         //  458752
  float* Hs    = wsf + 9748480;         //  458752
  float* wT    = wsf + 10207232;        //   36864 (3*64*192)
  float* w3s   = wsf + 10244096;        //   18432 (stem 32*9*64)
  float* w34   = wsf + 10262528;        //   73728 (p4 64*9*128)
  float* w35   = wsf + 10336256;        //  294912 (p5 128*9*256)

  k_wtrans<<<144, 256, 0, stream>>>(in_w, dt_w, B_w, C_w, wT);
  k_cwt2<<<72, 256, 0, stream>>>(stem_w, w3s, 64, 32);
  k_cwt2<<<288, 256, 0, stream>>>(p4_w, w34, 128, 64);
  k_cwt2<<<1152, 256, 0, stream>>>(p5_w, w35, 256, 128);

  // stem: [8,32,112,112] -> [8,64,56,56]; OWT=7 (SPAN 28, GWX 2, COG 1) -> 896 blocks
  k_conv<32, 64, 112, 112, 7, 16><<<896, 256, 0, stream>>>(
      x, w3s, stem_g, stem_b, stem_m, stem_v, x0);

  const float* xi = x0;
  for (int i = 0; i < 3; ++i) {
    k_proj<<<392, 256, 0, stream>>>(xi, wT + i * 64 * PD, dt_b + i * 32, Pb);
    k_scan1<<<1792, 256, 0, stream>>>(Pb, A_log + i * 2048, hfin, Pc);
    k_scan2<<<64, 256, 0, stream>>>(hfin, Pc, Hs);
    k_scan3<<<1792, 256, 0, stream>>>(Pb, A_log + i * 2048, Hs, Dp + i * 32,
                                      stout + (size_t)i * 51380224, yb);
    float* dst = (i == 2) ? p3out : ((i == 0) ? x1 : x0);
    k_outproj<<<392, 256, 0, stream>>>(xi, yb, out_w + i * 2048, dst);
    xi = dst;
  }

  // p4: [8,64,56,56] -> [8,128,28,28]; OWT=7 (SPAN 28, GWX 1, COG 2) -> 448 blocks
  k_conv<64, 128, 56, 56, 7, 16><<<448, 256, 0, stream>>>(
      p3out, w34, p4_g, p4_b, p4_m, p4_v, p4out);
  // p5: [8,128,28,28] -> [8,256,14,14]; OWT=4 (SPAN 16, GWX 1, COG 4) -> 448 blocks
  k_conv<128, 256, 28, 28, 4, 16><<<448, 256, 0, stream>>>(
      p4out, w35, p5_g, p5_b, p5_m, p5_v, p5out);
}